// Round 1
// baseline (1623.109 us; speedup 1.0000x reference)
//
#include <hip/hip_runtime.h>

#define BT   8192
#define CINC 256
#define NKC  4
#define HID  64
#define TEMPC 34.0f
#define KSPB 4   // KAN samples per block

// ---------------- K1: Attention2D ----------------
__global__ __launch_bounds__(256) void attn_kernel(
    const float* __restrict__ x,
    const float* __restrict__ fc1_w, const float* __restrict__ fc1_b,
    const float* __restrict__ fc2_w, const float* __restrict__ fc2_b,
    float* __restrict__ attn_out)
{
    __shared__ float pooled[CINC];
    __shared__ float part[HID][4];
    __shared__ float hid[HID];
    __shared__ float logit[NKC];
    const int b = blockIdx.x;
    const int tid = threadIdx.x;

    // pooled[c] = mean over 16 pixels
    const float4* xp = (const float4*)(x + ((size_t)b * CINC + tid) * 16);
    float4 v0 = xp[0], v1 = xp[1], v2 = xp[2], v3 = xp[3];
    float s = (v0.x + v0.y + v0.z + v0.w) + (v1.x + v1.y + v1.z + v1.w)
            + (v2.x + v2.y + v2.z + v2.w) + (v3.x + v3.y + v3.z + v3.w);
    pooled[tid] = s * (1.0f / 16.0f);
    __syncthreads();

    // fc1: 4 partial threads per hidden unit
    {
        const int h = tid >> 2, pt = tid & 3;
        const float* wr = fc1_w + h * CINC + pt * 64;
        const float* pr = pooled + pt * 64;
        float acc = 0.f;
        #pragma unroll 16
        for (int c = 0; c < 64; ++c) acc += pr[c] * wr[c];
        part[h][pt] = acc;
    }
    __syncthreads();
    if (tid < HID) {
        float a = part[tid][0] + part[tid][1] + part[tid][2] + part[tid][3] + fc1_b[tid];
        hid[tid] = fmaxf(a, 0.f);
    }
    __syncthreads();

    // fc2: one wave per kernel-bank logit
    {
        const int k = tid >> 6, lane = tid & 63;
        float p = hid[lane] * fc2_w[k * HID + lane];
        #pragma unroll
        for (int off = 32; off > 0; off >>= 1) p += __shfl_down(p, off);
        if (lane == 0) logit[k] = p + fc2_b[k];
    }
    __syncthreads();

    if (tid == 0) {
        float l0 = logit[0], l1 = logit[1], l2 = logit[2], l3 = logit[3];
        float m = fmaxf(fmaxf(l0, l1), fmaxf(l2, l3));
        float e0 = __expf((l0 - m) * (1.0f / TEMPC));
        float e1 = __expf((l1 - m) * (1.0f / TEMPC));
        float e2 = __expf((l2 - m) * (1.0f / TEMPC));
        float e3 = __expf((l3 - m) * (1.0f / TEMPC));
        float inv = 1.0f / (e0 + e1 + e2 + e3);
        *(float4*)(attn_out + (size_t)b * 4) = make_float4(e0 * inv, e1 * inv, e2 * inv, e3 * inv);
    }
}

// ---------------- K2: conv GEMM + attention combine -> feat[B,256] ----------
// M rows = sample*4 + pos (pos = h*2+w), N cols = k*64 + o, K = c*9 + i*3 + j
__global__ __launch_bounds__(256) void conv_kernel(
    const float* __restrict__ x, const float* __restrict__ weight,
    const float* __restrict__ bias, const float* __restrict__ attn,
    float* __restrict__ feat)
{
    __shared__ float X_lds[4][16][16];     // [c_local][pixel][sample] 4 KB
    __shared__ float B_lds[36][256];       // [t][n]                  36 KB
    __shared__ float feat_lds[16][256];    // [sample][o*4+pos]       16 KB
    __shared__ float attn_s[16][4];

    const int tid = threadIdx.x;
    const int ty = tid >> 4;        // sample 0..15
    const int tx = tid & 15;        // col group 0..15 (cols tx*16..tx*16+15)
    const int b0 = blockIdx.x * 16;

    const int acl = (tid >> 2) & 3; // staging: channel local
    const int ar4 = tid & 3;        // staging: x row

    float4 acc[4][4];               // [pos][quad of 4 cols]
    #pragma unroll
    for (int p = 0; p < 4; ++p)
        #pragma unroll
        for (int q = 0; q < 4; ++q) acc[p][q] = make_float4(0.f, 0.f, 0.f, 0.f);

    for (int it = 0; it < 64; ++it) {
        const int cc0 = it * 4;
        // global loads (overlap prior compute of other waves)
        const float4 xv = *(const float4*)(x + (((size_t)(b0 + ty) * CINC + cc0 + acl) * 16 + ar4 * 4));
        const float4* wsrc = (const float4*)(weight + (size_t)tid * 2304 + cc0 * 9);
        float4 wv[9];
        #pragma unroll
        for (int q = 0; q < 9; ++q) wv[q] = wsrc[q];

        __syncthreads();  // prior compute done -> safe to overwrite LDS
        X_lds[acl][ar4 * 4 + 0][ty] = xv.x;
        X_lds[acl][ar4 * 4 + 1][ty] = xv.y;
        X_lds[acl][ar4 * 4 + 2][ty] = xv.z;
        X_lds[acl][ar4 * 4 + 3][ty] = xv.w;
        #pragma unroll
        for (int q = 0; q < 9; ++q) {
            B_lds[q * 4 + 0][tid] = wv[q].x;
            B_lds[q * 4 + 1][tid] = wv[q].y;
            B_lds[q * 4 + 2][tid] = wv[q].z;
            B_lds[q * 4 + 3][tid] = wv[q].w;
        }
        __syncthreads();

        #pragma unroll
        for (int t = 0; t < 36; ++t) {
            const int c = t / 9;
            const int rr = t % 9;
            const int p = (rr / 3) * 4 + (rr % 3);
            const float a0 = X_lds[c][p][ty];      // pos (0,0)
            const float a1 = X_lds[c][p + 1][ty];  // pos (0,1)
            const float a2 = X_lds[c][p + 4][ty];  // pos (1,0)
            const float a3 = X_lds[c][p + 5][ty];  // pos (1,1)
            const float4* br = (const float4*)&B_lds[t][tx * 16];
            #pragma unroll
            for (int q = 0; q < 4; ++q) {
                const float4 w = br[q];
                acc[0][q].x += a0 * w.x; acc[0][q].y += a0 * w.y; acc[0][q].z += a0 * w.z; acc[0][q].w += a0 * w.w;
                acc[1][q].x += a1 * w.x; acc[1][q].y += a1 * w.y; acc[1][q].z += a1 * w.z; acc[1][q].w += a1 * w.w;
                acc[2][q].x += a2 * w.x; acc[2][q].y += a2 * w.y; acc[2][q].z += a2 * w.z; acc[2][q].w += a2 * w.w;
                acc[3][q].x += a3 * w.x; acc[3][q].y += a3 * w.y; acc[3][q].z += a3 * w.z; acc[3][q].w += a3 * w.w;
            }
        }
    }

    // ---- epilogue: combine with attention into feat_lds ----
    if (tid < 64) {
        const int s = tid >> 2, k = tid & 3;
        attn_s[s][k] = attn[(size_t)(b0 + s) * 4 + k];
    }
    {
        float* fz = &feat_lds[0][0];
        #pragma unroll
        for (int e = 0; e < 16; ++e) fz[e * 256 + tid] = 0.f;
    }
    __syncthreads();

    const int kgrp = tx >> 2;             // all 16 cols of this thread share k
    const int obase = (tx & 3) * 16;
    for (int ph = 0; ph < 4; ++ph) {
        if (kgrp == ph) {
            const float aw = attn_s[ty][kgrp];
            #pragma unroll
            for (int pos = 0; pos < 4; ++pos)
                #pragma unroll
                for (int q = 0; q < 4; ++q) {
                    float* f = &feat_lds[ty][(obase + q * 4) * 4 + pos];
                    const float4 v = acc[pos][q];
                    f[0]  += aw * v.x;
                    f[4]  += aw * v.y;
                    f[8]  += aw * v.z;
                    f[12] += aw * v.w;
                }
        }
        __syncthreads();
    }

    // store feat (+ aggregated bias), coalesced float4
    {
        const int s = ty;
        const int i0 = tx * 16;
        const float a0 = attn_s[s][0], a1 = attn_s[s][1], a2 = attn_s[s][2], a3 = attn_s[s][3];
        float* dst = feat + (size_t)(b0 + s) * 256 + i0;
        #pragma unroll
        for (int q = 0; q < 4; ++q) {
            const int o = (i0 >> 2) + q;
            const float bb = a0 * bias[o] + a1 * bias[64 + o] + a2 * bias[128 + o] + a3 * bias[192 + o];
            float4 v = *(const float4*)&feat_lds[s][i0 + q * 4];
            v.x += bb; v.y += bb; v.z += bb; v.w += bb;
            *(float4*)(dst + q * 4) = v;
        }
    }
}

// ---------------- K3: KANLinear -> out[B,64] ----------------
__global__ __launch_bounds__(256) void kan_kernel(
    const float* __restrict__ feat, const float* __restrict__ base_w,
    const float* __restrict__ spline_w, const float* __restrict__ scaler,
    float* __restrict__ out)
{
    __shared__ float fl[KSPB][CINC];       // feat, overwritten with silu(feat)
    __shared__ float bl[KSPB][CINC][8];    // B-spline bases
    const int tid = threadIdx.x;
    const int b0 = blockIdx.x * KSPB;

    // stage feat: KSPB*256 = 1024 floats = 256 float4
    {
        const float4* fg = (const float4*)(feat + (size_t)b0 * CINC);
        ((float4*)&fl[0][0])[tid] = fg[tid];
    }
    __syncthreads();

    // grid, bit-identical to reference: g[u] = float(u-3)*h + GMIN, h = 0.4
    float g[12];
    #pragma unroll
    for (int u = 0; u < 12; ++u) g[u] = (float)(u - 3) * 0.4f + (-1.0f);

    // phase 1: silu + Cox-de-Boor bases
    #pragma unroll
    for (int e = 0; e < KSPB; ++e) {
        const int pair = e * 256 + tid;
        const int s = pair >> 8, i = pair & 255;
        const float xv = fl[s][i];
        float t0[11];
        #pragma unroll
        for (int t = 0; t < 11; ++t)
            t0[t] = (xv >= g[t] && xv < g[t + 1]) ? 1.f : 0.f;
        float t1[10];
        #pragma unroll
        for (int t = 0; t < 10; ++t)
            t1[t] = (xv - g[t]) / (g[t + 1] - g[t]) * t0[t]
                  + (g[t + 2] - xv) / (g[t + 2] - g[t + 1]) * t0[t + 1];
        float t2[9];
        #pragma unroll
        for (int t = 0; t < 9; ++t)
            t2[t] = (xv - g[t]) / (g[t + 2] - g[t]) * t1[t]
                  + (g[t + 3] - xv) / (g[t + 3] - g[t + 1]) * t1[t + 1];
        float t3[8];
        #pragma unroll
        for (int t = 0; t < 8; ++t)
            t3[t] = (xv - g[t]) / (g[t + 3] - g[t]) * t2[t]
                  + (g[t + 4] - xv) / (g[t + 4] - g[t + 1]) * t2[t + 1];
        const float sv = xv / (1.f + __expf(-xv));
        fl[s][i] = sv;  // only this thread read this slot in phase 1
        float4* bp = (float4*)&bl[s][i][0];
        bp[0] = make_float4(t3[0], t3[1], t3[2], t3[3]);
        bp[1] = make_float4(t3[4], t3[5], t3[6], t3[7]);
    }
    __syncthreads();

    // phase 2: per (sample, o) reduction over 256 features
    const int slot = tid >> 6;   // sample within block (one wave per sample)
    const int o = tid & 63;
    const float* bwr = base_w + o * CINC;
    const float* scr = scaler + o * CINC;
    const float4* swr = (const float4*)(spline_w + (size_t)o * CINC * 8);
    float acc = 0.f;
    #pragma unroll 4
    for (int i = 0; i < CINC; ++i) {
        const float bw = bwr[i], sc = scr[i];
        const float4 w0 = swr[2 * i], w1 = swr[2 * i + 1];
        const float sv = fl[slot][i];
        const float4* bp = (const float4*)&bl[slot][i][0];
        const float4 u0 = bp[0], u1 = bp[1];
        const float d = u0.x * w0.x + u0.y * w0.y + u0.z * w0.z + u0.w * w0.w
                      + u1.x * w1.x + u1.y * w1.y + u1.z * w1.z + u1.w * w1.w;
        acc += sv * bw + sc * d;
    }
    out[(size_t)(b0 + slot) * 64 + o] = acc;
}

extern "C" void kernel_launch(void* const* d_in, const int* in_sizes, int n_in,
                              void* d_out, int out_size, void* d_ws, size_t ws_size,
                              hipStream_t stream) {
    const float* x          = (const float*)d_in[0];
    const float* weight     = (const float*)d_in[1];
    const float* bias       = (const float*)d_in[2];
    const float* fc1_w      = (const float*)d_in[3];
    const float* fc1_b      = (const float*)d_in[4];
    const float* fc2_w      = (const float*)d_in[5];
    const float* fc2_b      = (const float*)d_in[6];
    const float* kan_base_w = (const float*)d_in[7];
    const float* kan_spline = (const float*)d_in[8];
    const float* kan_scaler = (const float*)d_in[9];
    float* out = (float*)d_out;

    float* attn = (float*)d_ws;                 // 8192*4 floats
    float* feat = attn + (size_t)BT * 4;        // 8192*256 floats

    attn_kernel<<<BT, 256, 0, stream>>>(x, fc1_w, fc1_b, fc2_w, fc2_b, attn);
    conv_kernel<<<BT / 16, 256, 0, stream>>>(x, weight, bias, attn, feat);
    kan_kernel<<<BT / KSPB, 256, 0, stream>>>(feat, kan_base_w, kan_spline, kan_scaler, out);
}

// Round 2
// 447.137 us; speedup vs baseline: 3.6300x; 3.6300x over previous
//
#include <hip/hip_runtime.h>

#define BT   8192
#define CINC 256
#define HID  64
#define NKC  4
#define TEMPC 34.0f
#define MS   16     // samples per conv block

typedef _Float16 half8  __attribute__((ext_vector_type(8)));
typedef _Float16 half4v __attribute__((ext_vector_type(4)));
typedef _Float16 half2v __attribute__((ext_vector_type(2)));
typedef float    floatx4  __attribute__((ext_vector_type(4)));
typedef float    floatx16 __attribute__((ext_vector_type(16)));

// ---------------- K0: weight pre-transform -> W3[step][n][32c] fp16 -------
// step = cc*9 + ij  (cc = channel chunk of 32, ij = i*3+j)
__global__ __launch_bounds__(256) void w3_transform(
    const float* __restrict__ weight, _Float16* __restrict__ W3)
{
    const int n = blockIdx.x;      // 0..255  (= kbank*64 + o)
    const int c = threadIdx.x;     // 0..255
    const float* src = weight + ((size_t)n * 256 + c) * 9;
    const int cc = c >> 5, ci = c & 31;
    #pragma unroll
    for (int ij = 0; ij < 9; ++ij) {
        W3[((size_t)(cc * 9 + ij) * 256 + n) * 32 + ci] = (_Float16)src[ij];
    }
}

// ---------------- K1: Attention2D (unchanged) ----------------
__global__ __launch_bounds__(256) void attn_kernel(
    const float* __restrict__ x,
    const float* __restrict__ fc1_w, const float* __restrict__ fc1_b,
    const float* __restrict__ fc2_w, const float* __restrict__ fc2_b,
    float* __restrict__ attn_out)
{
    __shared__ float pooled[CINC];
    __shared__ float part[HID][4];
    __shared__ float hid[HID];
    __shared__ float logit[NKC];
    const int b = blockIdx.x;
    const int tid = threadIdx.x;

    const float4* xp = (const float4*)(x + ((size_t)b * CINC + tid) * 16);
    float4 v0 = xp[0], v1 = xp[1], v2 = xp[2], v3 = xp[3];
    float s = (v0.x + v0.y + v0.z + v0.w) + (v1.x + v1.y + v1.z + v1.w)
            + (v2.x + v2.y + v2.z + v2.w) + (v3.x + v3.y + v3.z + v3.w);
    pooled[tid] = s * (1.0f / 16.0f);
    __syncthreads();

    {
        const int h = tid >> 2, pt = tid & 3;
        const float* wr = fc1_w + h * CINC + pt * 64;
        const float* pr = pooled + pt * 64;
        float acc = 0.f;
        #pragma unroll 16
        for (int c = 0; c < 64; ++c) acc += pr[c] * wr[c];
        part[h][pt] = acc;
    }
    __syncthreads();
    if (tid < HID) {
        float a = part[tid][0] + part[tid][1] + part[tid][2] + part[tid][3] + fc1_b[tid];
        hid[tid] = fmaxf(a, 0.f);
    }
    __syncthreads();

    {
        const int k = tid >> 6, lane = tid & 63;
        float p = hid[lane] * fc2_w[k * HID + lane];
        #pragma unroll
        for (int off = 32; off > 0; off >>= 1) p += __shfl_down(p, off);
        if (lane == 0) logit[k] = p + fc2_b[k];
    }
    __syncthreads();

    if (tid == 0) {
        float l0 = logit[0], l1 = logit[1], l2 = logit[2], l3 = logit[3];
        float m = fmaxf(fmaxf(l0, l1), fmaxf(l2, l3));
        float e0 = __expf((l0 - m) * (1.0f / TEMPC));
        float e1 = __expf((l1 - m) * (1.0f / TEMPC));
        float e2 = __expf((l2 - m) * (1.0f / TEMPC));
        float e3 = __expf((l3 - m) * (1.0f / TEMPC));
        float inv = 1.0f / (e0 + e1 + e2 + e3);
        *(float4*)(attn_out + (size_t)b * 4) = make_float4(e0 * inv, e1 * inv, e2 * inv, e3 * inv);
    }
}

// ---------------- K2: MFMA conv GEMM + attn combine -> feat[B,256] --------
// rows m = s*4+pos (4 row-tiles), cols n = kbank*64+o (16 col-tiles)
// wave wv owns col-tiles {wv, wv+4, wv+8, wv+12} -> in-register k-combine
__global__ __launch_bounds__(256, 2) void conv_mfma(
    const float* __restrict__ x, const _Float16* __restrict__ W3,
    const float* __restrict__ bias, const float* __restrict__ attn,
    float* __restrict__ feat)
{
    // Xs: [s][p][c] halves, p-stride 40, s-stride 656 (bank-tuned, 16B aligned)
    __shared__ _Float16 Xs[MS * 656];
    __shared__ float attn_s[MS][4];

    const int tid = threadIdx.x;
    const int wv = tid >> 6, lane = tid & 63;
    const int nl = lane & 15, q = lane >> 4;
    const int b0 = blockIdx.x * MS;

    if (tid < MS * 4) attn_s[tid >> 2][tid & 3] = attn[(size_t)(b0 + (tid >> 2)) * 4 + (tid & 3)];

    // A-fragment lane base (halves): s-part + pos-part + k-part (rt,ij added later)
    const int posr = nl & 3;
    const int aLane = (nl >> 2) * 656 + ((posr >> 1) * 4 + (posr & 1)) * 40 + q * 8;
    // B-fragment lane offsets (halves) per kbank
    int lbW[4];
    #pragma unroll
    for (int kb = 0; kb < 4; ++kb) lbW[kb] = ((wv + 4 * kb) * 16 + nl) * 32 + q * 8;

    // X staging: thread -> (sample, c-pair); reads 2 rows of 16 pixels (128B)
    const int xs_ = tid >> 4, xcp = tid & 15;
    const float* xg = x + ((size_t)(b0 + xs_) * 256 + xcp * 2) * 16;
    _Float16* xd = &Xs[xs_ * 656 + xcp * 2];

    floatx4 acc[4][4];
    #pragma unroll
    for (int rt = 0; rt < 4; ++rt)
        #pragma unroll
        for (int kb = 0; kb < 4; ++kb) acc[rt][kb] = floatx4{0.f, 0.f, 0.f, 0.f};

    floatx16 r0 = *(const floatx16*)(xg);
    floatx16 r1 = *(const floatx16*)(xg + 16);

    for (int cc = 0; cc < 8; ++cc) {
        __syncthreads();   // prior chunk's Xs readers done
        #pragma unroll
        for (int p = 0; p < 16; ++p) {
            half2v h;
            h[0] = (_Float16)r0[p];
            h[1] = (_Float16)r1[p];
            *(half2v*)&xd[p * 40] = h;
        }
        if (cc < 7) {      // prefetch next chunk's x during this chunk's compute
            r0 = *(const floatx16*)(xg + (cc + 1) * 512);
            r1 = *(const floatx16*)(xg + (cc + 1) * 512 + 16);
        }
        __syncthreads();   // Xs ready

        #pragma unroll 3
        for (int ij = 0; ij < 9; ++ij) {
            const int step = cc * 9 + ij;
            const int p0 = (ij / 3) * 4 + (ij % 3);
            const _Float16* wstep = W3 + (size_t)step * 8192;
            half8 bF[4];
            #pragma unroll
            for (int kb = 0; kb < 4; ++kb) bF[kb] = *(const half8*)(wstep + lbW[kb]);
            half8 aF[4];
            #pragma unroll
            for (int rt = 0; rt < 4; ++rt) aF[rt] = *(const half8*)&Xs[rt * 2624 + aLane + p0 * 40];
            #pragma unroll
            for (int rt = 0; rt < 4; ++rt)
                #pragma unroll
                for (int kb = 0; kb < 4; ++kb)
                    acc[rt][kb] = __builtin_amdgcn_mfma_f32_16x16x32_f16(aF[rt], bF[kb], acc[rt][kb], 0, 0, 0);
        }
    }

    // epilogue: feat[s][o*4+pos] = sum_k attn[s][k]*(y_k + bias_k)
    const int o = wv * 16 + nl;
    const float bb0 = bias[o], bb1 = bias[64 + o], bb2 = bias[128 + o], bb3 = bias[192 + o];
    #pragma unroll
    for (int rt = 0; rt < 4; ++rt) {
        const int s = rt * 4 + q;
        const float a0 = attn_s[s][0], a1 = attn_s[s][1], a2 = attn_s[s][2], a3 = attn_s[s][3];
        const float badd = a0 * bb0 + a1 * bb1 + a2 * bb2 + a3 * bb3;
        float4 f;
        f.x = a0 * acc[rt][0][0] + a1 * acc[rt][1][0] + a2 * acc[rt][2][0] + a3 * acc[rt][3][0] + badd;
        f.y = a0 * acc[rt][0][1] + a1 * acc[rt][1][1] + a2 * acc[rt][2][1] + a3 * acc[rt][3][1] + badd;
        f.z = a0 * acc[rt][0][2] + a1 * acc[rt][1][2] + a2 * acc[rt][2][2] + a3 * acc[rt][3][2] + badd;
        f.w = a0 * acc[rt][0][3] + a1 * acc[rt][1][3] + a2 * acc[rt][2][3] + a3 * acc[rt][3][3] + badd;
        *(float4*)&feat[(size_t)(b0 + s) * 256 + o * 4] = f;
    }
}

// ---------------- K3: KANLinear -> out[B,64] ----------------
// phase 1: bases+silu to LDS (fp16). phase 2: wave lanes span feature dim
// (coalesced global reads), butterfly-reduce per (sample, o).
__global__ __launch_bounds__(256) void kan_kernel(
    const float* __restrict__ feat, const float* __restrict__ base_w,
    const float* __restrict__ spline_w, const float* __restrict__ scaler,
    float* __restrict__ out)
{
    __shared__ _Float16 fl[8 * 256];        // silu(feat)
    __shared__ _Float16 bl[8 * 256 * 12];   // bases, 12-half stride (bank pad)
    const int tid = threadIdx.x;
    const int wv = tid >> 6, lane = tid & 63;
    const int b0 = blockIdx.x * 8;

    float g[12];
    #pragma unroll
    for (int u = 0; u < 12; ++u) g[u] = (float)(u - 3) * 0.4f - 1.0f;

    #pragma unroll
    for (int s = 0; s < 8; ++s) {
        const float xv = feat[(size_t)(b0 + s) * 256 + tid];
        float t0[11];
        #pragma unroll
        for (int t = 0; t < 11; ++t)
            t0[t] = (xv >= g[t] && xv < g[t + 1]) ? 1.f : 0.f;
        float t1[10];
        #pragma unroll
        for (int t = 0; t < 10; ++t)
            t1[t] = (xv - g[t]) / (g[t + 1] - g[t]) * t0[t]
                  + (g[t + 2] - xv) / (g[t + 2] - g[t + 1]) * t0[t + 1];
        float t2[9];
        #pragma unroll
        for (int t = 0; t < 9; ++t)
            t2[t] = (xv - g[t]) / (g[t + 2] - g[t]) * t1[t]
                  + (g[t + 3] - xv) / (g[t + 3] - g[t + 1]) * t1[t + 1];
        float t3[8];
        #pragma unroll
        for (int t = 0; t < 8; ++t)
            t3[t] = (xv - g[t]) / (g[t + 3] - g[t]) * t2[t]
                  + (g[t + 4] - xv) / (g[t + 4] - g[t + 1]) * t2[t + 1];
        fl[s * 256 + tid] = (_Float16)(xv / (1.f + __expf(-xv)));
        const int bb = (s * 256 + tid) * 12;
        half4v lo, hi;
        lo[0] = (_Float16)t3[0]; lo[1] = (_Float16)t3[1];
        lo[2] = (_Float16)t3[2]; lo[3] = (_Float16)t3[3];
        hi[0] = (_Float16)t3[4]; hi[1] = (_Float16)t3[5];
        hi[2] = (_Float16)t3[6]; hi[3] = (_Float16)t3[7];
        *(half4v*)&bl[bb] = lo;
        *(half4v*)&bl[bb + 4] = hi;
    }
    __syncthreads();

    const int s0 = wv * 2;
    for (int o = 0; o < 64; ++o) {
        float p0 = 0.f, p1 = 0.f;
        #pragma unroll
        for (int ch = 0; ch < 4; ++ch) {
            const int i = ch * 64 + lane;
            const float bw = base_w[o * 256 + i];
            const float sc = scaler[o * 256 + i];
            const float4 wa = *(const float4*)&spline_w[((size_t)o * 256 + i) * 8];
            const float4 wb = *(const float4*)&spline_w[((size_t)o * 256 + i) * 8 + 4];
            {
                const int bb = (s0 * 256 + i) * 12;
                half4v ul = *(const half4v*)&bl[bb];
                half4v uh = *(const half4v*)&bl[bb + 4];
                float d = (float)ul[0] * wa.x + (float)ul[1] * wa.y + (float)ul[2] * wa.z + (float)ul[3] * wa.w
                        + (float)uh[0] * wb.x + (float)uh[1] * wb.y + (float)uh[2] * wb.z + (float)uh[3] * wb.w;
                p0 += (float)fl[s0 * 256 + i] * bw + sc * d;
            }
            {
                const int bb = ((s0 + 1) * 256 + i) * 12;
                half4v ul = *(const half4v*)&bl[bb];
                half4v uh = *(const half4v*)&bl[bb + 4];
                float d = (float)ul[0] * wa.x + (float)ul[1] * wa.y + (float)ul[2] * wa.z + (float)ul[3] * wa.w
                        + (float)uh[0] * wb.x + (float)uh[1] * wb.y + (float)uh[2] * wb.z + (float)uh[3] * wb.w;
                p1 += (float)fl[(s0 + 1) * 256 + i] * bw + sc * d;
            }
        }
        #pragma unroll
        for (int off = 32; off >= 1; off >>= 1) {
            p0 += __shfl_xor(p0, off);
            p1 += __shfl_xor(p1, off);
        }
        if (lane == 0) {
            out[(size_t)(b0 + s0) * 64 + o] = p0;
            out[(size_t)(b0 + s0 + 1) * 64 + o] = p1;
        }
    }
}

extern "C" void kernel_launch(void* const* d_in, const int* in_sizes, int n_in,
                              void* d_out, int out_size, void* d_ws, size_t ws_size,
                              hipStream_t stream) {
    const float* x          = (const float*)d_in[0];
    const float* weight     = (const float*)d_in[1];
    const float* bias       = (const float*)d_in[2];
    const float* fc1_w      = (const float*)d_in[3];
    const float* fc1_b      = (const float*)d_in[4];
    const float* fc2_w      = (const float*)d_in[5];
    const float* fc2_b      = (const float*)d_in[6];
    const float* kan_base_w = (const float*)d_in[7];
    const float* kan_spline = (const float*)d_in[8];
    const float* kan_scaler = (const float*)d_in[9];
    float* out = (float*)d_out;

    // ws layout: attn (128KB) | feat (8MB) | W3 fp16 (1.125MB)
    float* attn = (float*)d_ws;
    float* feat = attn + (size_t)BT * 4;
    _Float16* W3 = (_Float16*)(feat + (size_t)BT * 256);

    w3_transform<<<256, 256, 0, stream>>>(weight, W3);
    attn_kernel<<<BT, 256, 0, stream>>>(x, fc1_w, fc1_b, fc2_w, fc2_b, attn);
    conv_mfma<<<BT / MS, 256, 0, stream>>>(x, W3, bias, attn, feat);
    kan_kernel<<<BT / 8, 256, 0, stream>>>(feat, kan_base_w, kan_spline, kan_scaler, out);
}

// Round 3
// 306.950 us; speedup vs baseline: 5.2879x; 1.4567x over previous
//
#include <hip/hip_runtime.h>

#define BT   8192
#define CINC 256
#define HID  64
#define NKC  4
#define MS   16     // samples per conv block

typedef _Float16 half8  __attribute__((ext_vector_type(8)));
typedef _Float16 half4v __attribute__((ext_vector_type(4)));
typedef _Float16 half2v __attribute__((ext_vector_type(2)));
typedef float    floatx4  __attribute__((ext_vector_type(4)));
typedef float    floatx16 __attribute__((ext_vector_type(16)));

// ---------------- K0a: conv weight pre-transform -> W3[step][256n][32c] ----
// step = cc*9 + ij  (cc = channel chunk of 32, ij = i*3+j)
__global__ __launch_bounds__(256) void w3_transform(
    const float* __restrict__ weight, _Float16* __restrict__ W3)
{
    const int n = blockIdx.x;      // 0..255  (= kbank*64 + o)
    const int c = threadIdx.x;     // 0..255
    const float* src = weight + ((size_t)n * 256 + c) * 9;
    const int cc = c >> 5, ci = c & 31;
    #pragma unroll
    for (int ij = 0; ij < 9; ++ij) {
        W3[((size_t)(cc * 9 + ij) * 256 + n) * 32 + ci] = (_Float16)src[ij];
    }
}

// ---------------- K0b: KAN weight pre-transform -> Wk3[step][64n][32k] ----
// k-global: [0,256) = base_w[n][k]; [256,2304): i=(k-256)>>3, g=(k-256)&7 ->
// spline_w[n][i][g] * scaler[n][i]
__global__ __launch_bounds__(256) void wk3_transform(
    const float* __restrict__ base_w, const float* __restrict__ spline_w,
    const float* __restrict__ scaler, _Float16* __restrict__ Wk3)
{
    const int st = blockIdx.x;     // 0..71
    const int tid = threadIdx.x;
    #pragma unroll
    for (int u = 0; u < 8; ++u) {
        const int idx = u * 256 + tid;       // n*32 + kk
        const int n = idx >> 5, kk = idx & 31;
        const int k = st * 32 + kk;
        float v;
        if (k < 256) {
            v = base_w[n * 256 + k];
        } else {
            const int r = k - 256;
            const int i = r >> 3, g = r & 7;
            v = spline_w[((size_t)n * 256 + i) * 8 + g] * scaler[n * 256 + i];
        }
        Wk3[(size_t)st * 2048 + idx] = (_Float16)v;
    }
}

// B-spline bases (cubic, grid 5, order 3) -> 8 fp16 values
__device__ __forceinline__ void bases8(float xv, _Float16* dst) {
    float g[12];
    #pragma unroll
    for (int u = 0; u < 12; ++u) g[u] = (float)(u - 3) * 0.4f - 1.0f;
    float t0[11];
    #pragma unroll
    for (int t = 0; t < 11; ++t)
        t0[t] = (xv >= g[t] && xv < g[t + 1]) ? 1.f : 0.f;
    float t1[10];
    #pragma unroll
    for (int t = 0; t < 10; ++t)
        t1[t] = (xv - g[t]) / (g[t + 1] - g[t]) * t0[t]
              + (g[t + 2] - xv) / (g[t + 2] - g[t + 1]) * t0[t + 1];
    float t2[9];
    #pragma unroll
    for (int t = 0; t < 9; ++t)
        t2[t] = (xv - g[t]) / (g[t + 2] - g[t]) * t1[t]
              + (g[t + 3] - xv) / (g[t + 3] - g[t + 1]) * t1[t + 1];
    half8 hb;
    #pragma unroll
    for (int t = 0; t < 8; ++t) {
        float b = (xv - g[t]) / (g[t + 3] - g[t]) * t2[t]
                + (g[t + 4] - xv) / (g[t + 4] - g[t + 1]) * t2[t + 1];
        hb[t] = (_Float16)b;
    }
    *(half8*)dst = hb;
}

// ---------------- Fused: attn + dyn-conv (MFMA) + KAN (MFMA) -> out -------
__global__ __launch_bounds__(256, 2) void fused_kernel(
    const float* __restrict__ x, const _Float16* __restrict__ W3,
    const _Float16* __restrict__ Wk3, const float* __restrict__ bias,
    const float* __restrict__ fc1_w, const float* __restrict__ fc1_b,
    const float* __restrict__ fc2_w, const float* __restrict__ fc2_b,
    float* __restrict__ out)
{
    // Overlay: phase A = Xs (16*656 fp16, 20992 B) + pooled (16*260 f32, 16640 B)
    //          phase B = Act (16*2312 fp16, 73984 B)
    __shared__ __align__(16) char smem[16 * 2312 * 2];
    __shared__ float hid_lds[16 * 68];
    __shared__ float attn_s[16][4];

    _Float16* Xs   = (_Float16*)smem;
    float*    pooled = (float*)(smem + 20992);
    _Float16* Act  = (_Float16*)smem;

    const int tid = threadIdx.x;
    const int wv = tid >> 6, lane = tid & 63;
    const int nl = lane & 15, q = lane >> 4;
    const int b0 = blockIdx.x * MS;

    // conv A-fragment base (halves): sample part + pixel part + k part
    const int posr = nl & 3;
    const int aLane = (nl >> 2) * 656 + ((posr >> 1) * 4 + (posr & 1)) * 40 + q * 8;
    int lbW[4];
    #pragma unroll
    for (int kb = 0; kb < 4; ++kb) lbW[kb] = ((wv + 4 * kb) * 16 + nl) * 32 + q * 8;

    // x staging: thread -> (sample, channel pair)
    const int xs_ = tid >> 4, xcp = tid & 15;
    const float* xg = x + ((size_t)(b0 + xs_) * 256 + xcp * 2) * 16;
    _Float16* xd = &Xs[xs_ * 656 + xcp * 2];
    float* pd = &pooled[xs_ * 260 + xcp * 2];

    floatx4 acc[4][4];
    #pragma unroll
    for (int rt = 0; rt < 4; ++rt)
        #pragma unroll
        for (int kb = 0; kb < 4; ++kb) acc[rt][kb] = floatx4{0.f, 0.f, 0.f, 0.f};

    floatx16 r0 = *(const floatx16*)(xg);
    floatx16 r1 = *(const floatx16*)(xg + 16);

    for (int cc = 0; cc < 8; ++cc) {
        __syncthreads();   // prior chunk's Xs readers done
        #pragma unroll
        for (int p = 0; p < 16; ++p) {
            half2v h;
            h[0] = (_Float16)r0[p];
            h[1] = (_Float16)r1[p];
            *(half2v*)&xd[p * 40] = h;
        }
        // pooled accumulation from pristine fp32 values
        {
            float s0 = 0.f, s1 = 0.f;
            #pragma unroll
            for (int p = 0; p < 16; ++p) { s0 += r0[p]; s1 += r1[p]; }
            pd[cc * 32] = s0 * (1.0f / 16.0f);
            pd[cc * 32 + 1] = s1 * (1.0f / 16.0f);
        }
        if (cc < 7) {
            r0 = *(const floatx16*)(xg + (cc + 1) * 512);
            r1 = *(const floatx16*)(xg + (cc + 1) * 512 + 16);
        }
        __syncthreads();   // Xs + pooled chunk ready

        #pragma unroll 3
        for (int ij = 0; ij < 9; ++ij) {
            const int step = cc * 9 + ij;
            const int p0 = (ij / 3) * 4 + (ij % 3);
            const _Float16* wstep = W3 + (size_t)step * 8192;
            half8 bF[4];
            #pragma unroll
            for (int kb = 0; kb < 4; ++kb) bF[kb] = *(const half8*)(wstep + lbW[kb]);
            half8 aF[4];
            #pragma unroll
            for (int rt = 0; rt < 4; ++rt) aF[rt] = *(const half8*)&Xs[rt * 2624 + aLane + p0 * 40];
            #pragma unroll
            for (int rt = 0; rt < 4; ++rt)
                #pragma unroll
                for (int kb = 0; kb < 4; ++kb)
                    acc[rt][kb] = __builtin_amdgcn_mfma_f32_16x16x32_f16(aF[rt], bF[kb], acc[rt][kb], 0, 0, 0);
        }
    }

    // ---- attention: fc1 (VALU, pooled-broadcast) -> fc2+softmax (wave 0) ----
    // h = wv*16 + p*4 + q  (wave-major), s = nl
    {
        float facc[4];
        #pragma unroll
        for (int p = 0; p < 4; ++p) {
            const int h = wv * 16 + p * 4 + q;
            float a = fc1_b[h];
            const float4* wr = (const float4*)(fc1_w + h * 256);
            const float4* pr = (const float4*)(pooled + nl * 260);
            #pragma unroll 8
            for (int c4 = 0; c4 < 64; ++c4) {
                const float4 w = wr[c4], pv = pr[c4];
                a += w.x * pv.x + w.y * pv.y + w.z * pv.z + w.w * pv.w;
            }
            facc[p] = fmaxf(a, 0.f);
        }
        #pragma unroll
        for (int p = 0; p < 4; ++p) hid_lds[nl * 68 + wv * 16 + p * 4 + q] = facc[p];
    }
    __syncthreads();
    if (wv == 0) {
        const int s = lane >> 2, kb = lane & 3;
        float l = fc2_b[kb];
        #pragma unroll 8
        for (int h = 0; h < 64; ++h) l += hid_lds[s * 68 + h] * fc2_w[kb * 64 + h];
        float m = fmaxf(l, __shfl_xor(l, 1));
        m = fmaxf(m, __shfl_xor(m, 2));
        const float e = __expf((l - m) * (1.0f / 34.0f));
        float sm = e + __shfl_xor(e, 1);
        sm += __shfl_xor(sm, 2);
        attn_s[s][kb] = e / sm;
    }
    __syncthreads();   // attn ready; pooled/Xs reads all done -> Act region free

    // ---- epilogue: attn-combine in registers -> silu + bases -> Act (LDS) ----
    {
        const int o = wv * 16 + nl;
        const float bb0 = bias[o], bb1 = bias[64 + o], bb2 = bias[128 + o], bb3 = bias[192 + o];
        #pragma unroll
        for (int rt = 0; rt < 4; ++rt) {
            const int s = rt * 4 + q;
            const float a0 = attn_s[s][0], a1 = attn_s[s][1], a2 = attn_s[s][2], a3 = attn_s[s][3];
            const float badd = a0 * bb0 + a1 * bb1 + a2 * bb2 + a3 * bb3;
            float f[4];
            #pragma unroll
            for (int e = 0; e < 4; ++e)
                f[e] = a0 * acc[rt][0][e] + a1 * acc[rt][1][e]
                     + a2 * acc[rt][2][e] + a3 * acc[rt][3][e] + badd;
            half4v sv;
            #pragma unroll
            for (int e = 0; e < 4; ++e) sv[e] = (_Float16)(f[e] / (1.f + __expf(-f[e])));
            *(half4v*)&Act[s * 2312 + o * 4] = sv;
            #pragma unroll
            for (int e = 0; e < 4; ++e)
                bases8(f[e], &Act[s * 2312 + 256 + (o * 4 + e) * 8]);
        }
    }
    __syncthreads();

    // ---- KAN GEMM: out[16 s][64 o] += Act[16][2304] * Wk^T, 72 K-steps ----
    {
        floatx4 acc2 = floatx4{0.f, 0.f, 0.f, 0.f};
        const _Float16* wkb = Wk3 + ((size_t)(wv * 16 + nl) * 32 + q * 8);
        const _Float16* ab = &Act[nl * 2312 + q * 8];
        #pragma unroll 8
        for (int st = 0; st < 72; ++st) {
            const half8 aF = *(const half8*)(ab + st * 32);
            const half8 bF = *(const half8*)(wkb + (size_t)st * 2048);
            acc2 = __builtin_amdgcn_mfma_f32_16x16x32_f16(aF, bF, acc2, 0, 0, 0);
        }
        #pragma unroll
        for (int reg = 0; reg < 4; ++reg)
            out[(size_t)(b0 + q * 4 + reg) * 64 + wv * 16 + nl] = acc2[reg];
    }
}

extern "C" void kernel_launch(void* const* d_in, const int* in_sizes, int n_in,
                              void* d_out, int out_size, void* d_ws, size_t ws_size,
                              hipStream_t stream) {
    const float* x          = (const float*)d_in[0];
    const float* weight     = (const float*)d_in[1];
    const float* bias       = (const float*)d_in[2];
    const float* fc1_w      = (const float*)d_in[3];
    const float* fc1_b      = (const float*)d_in[4];
    const float* fc2_w      = (const float*)d_in[5];
    const float* fc2_b      = (const float*)d_in[6];
    const float* kan_base_w = (const float*)d_in[7];
    const float* kan_spline = (const float*)d_in[8];
    const float* kan_scaler = (const float*)d_in[9];
    float* out = (float*)d_out;

    // ws layout: W3 (72*8192 halves = 1.125 MB) | Wk3 (72*2048 halves = 288 KB)
    _Float16* W3  = (_Float16*)d_ws;
    _Float16* Wk3 = W3 + (size_t)72 * 8192;

    w3_transform<<<256, 256, 0, stream>>>(weight, W3);
    wk3_transform<<<72, 256, 0, stream>>>(kan_base_w, kan_spline, kan_scaler, Wk3);
    fused_kernel<<<BT / MS, 256, 0, stream>>>(x, W3, Wk3, bias, fc1_w, fc1_b,
                                              fc2_w, fc2_b, out);
}

// Round 4
// 276.621 us; speedup vs baseline: 5.8676x; 1.1096x over previous
//
#include <hip/hip_runtime.h>

#define BT   8192
#define MS   16     // samples per fused block

typedef _Float16 half8  __attribute__((ext_vector_type(8)));
typedef _Float16 half4v __attribute__((ext_vector_type(4)));
typedef float    floatx4  __attribute__((ext_vector_type(4)));
typedef float    floatx16 __attribute__((ext_vector_type(16)));

// ---------------- K0a: conv weight pre-transform -> W3[step][256n][32c] ----
__global__ __launch_bounds__(256) void w3_transform(
    const float* __restrict__ weight, _Float16* __restrict__ W3)
{
    const int n = blockIdx.x;      // 0..255  (= kbank*64 + o)
    const int c = threadIdx.x;     // 0..255
    const float* src = weight + ((size_t)n * 256 + c) * 9;
    const int cc = c >> 5, ci = c & 31;
    #pragma unroll
    for (int ij = 0; ij < 9; ++ij) {
        W3[((size_t)(cc * 9 + ij) * 256 + n) * 32 + ci] = (_Float16)src[ij];
    }
}

// ---------------- K0b: KAN + fc1 weight pre-transform ---------------------
// blocks 0..71:  Wk3[step][64n][32k]  (KAN merged weight)
// blocks 72..79: Wf3[step][64h][32k]  (fc1 weight)
__global__ __launch_bounds__(256) void wk3_transform(
    const float* __restrict__ base_w, const float* __restrict__ spline_w,
    const float* __restrict__ scaler, const float* __restrict__ fc1_w,
    _Float16* __restrict__ Wk3, _Float16* __restrict__ Wf3)
{
    const int st = blockIdx.x;
    const int tid = threadIdx.x;
    if (st < 72) {
        #pragma unroll
        for (int u = 0; u < 8; ++u) {
            const int idx = u * 256 + tid;       // n*32 + kk
            const int n = idx >> 5, kk = idx & 31;
            const int k = st * 32 + kk;
            float v;
            if (k < 256) {
                v = base_w[n * 256 + k];
            } else {
                const int r = k - 256;
                const int i = r >> 3, g = r & 7;
                v = spline_w[((size_t)n * 256 + i) * 8 + g] * scaler[n * 256 + i];
            }
            Wk3[(size_t)st * 2048 + idx] = (_Float16)v;
        }
    } else {
        const int st2 = st - 72;                 // 0..7
        #pragma unroll
        for (int u = 0; u < 8; ++u) {
            const int idx = u * 256 + tid;
            const int n = idx >> 5, kk = idx & 31;
            Wf3[(size_t)st2 * 2048 + idx] = (_Float16)fc1_w[n * 256 + st2 * 32 + kk];
        }
    }
}

// B-spline bases (cubic, grid 5, order 3). Divisions are by grid-constant
// differences -> written as multiply by compile-time-folded reciprocals.
__device__ __forceinline__ void bases8(float xv, _Float16* dst) {
    float g[12];
    #pragma unroll
    for (int u = 0; u < 12; ++u) g[u] = (float)(u - 3) * 0.4f - 1.0f;
    float dt[12];
    #pragma unroll
    for (int u = 0; u < 12; ++u) dt[u] = xv - g[u];
    float t0[11];
    #pragma unroll
    for (int t = 0; t < 11; ++t)
        t0[t] = (xv >= g[t] && xv < g[t + 1]) ? 1.f : 0.f;
    float t1[10];
    #pragma unroll
    for (int t = 0; t < 10; ++t)
        t1[t] = dt[t] * (1.0f / (g[t + 1] - g[t])) * t0[t]
              - dt[t + 2] * (1.0f / (g[t + 2] - g[t + 1])) * t0[t + 1];
    float t2[9];
    #pragma unroll
    for (int t = 0; t < 9; ++t)
        t2[t] = dt[t] * (1.0f / (g[t + 2] - g[t])) * t1[t]
              - dt[t + 3] * (1.0f / (g[t + 3] - g[t + 1])) * t1[t + 1];
    half8 hb;
    #pragma unroll
    for (int t = 0; t < 8; ++t) {
        float b = dt[t] * (1.0f / (g[t + 3] - g[t])) * t2[t]
                - dt[t + 4] * (1.0f / (g[t + 4] - g[t + 1])) * t2[t + 1];
        hb[t] = (_Float16)b;
    }
    *(half8*)dst = hb;
}

// ---------------- Fused: attn + dyn-conv (MFMA) + KAN (MFMA) -> out -------
// 512 threads = 8 waves. Conv: wave = (col-group cg = wv&3) x (row-half rh).
__global__ __launch_bounds__(512, 4) void fused_kernel(
    const float* __restrict__ x, const _Float16* __restrict__ W3,
    const _Float16* __restrict__ Wk3, const _Float16* __restrict__ Wf3,
    const float* __restrict__ bias, const float* __restrict__ fc1_b,
    const float* __restrict__ fc2_w, const float* __restrict__ fc2_b,
    float* __restrict__ out)
{
    // Overlay: phase A = Xs (16*656 fp16 = 20992 B) + Pl (16*264 fp16 = 8448 B)
    //          phase B = Act (16*2312 fp16 = 73984 B)
    __shared__ __align__(16) char smem[16 * 2312 * 2];
    __shared__ float hid_lds[16 * 68];
    __shared__ float attn_s[16][4];

    _Float16* Xs  = (_Float16*)smem;
    _Float16* Pl  = (_Float16*)(smem + 20992);   // pooled, fp16 A-layout
    _Float16* Act = (_Float16*)smem;

    const int tid = threadIdx.x;
    const int wv = tid >> 6, lane = tid & 63;
    const int nl = lane & 15, q = lane >> 4;
    const int cg = wv & 3, rh = wv >> 2;
    const int b0 = blockIdx.x * MS;

    // conv A-fragment base (halves): sample row + pixel + k part
    const int posr = nl & 3;
    const int aLane = (nl >> 2) * 656 + ((posr >> 1) * 4 + (posr & 1)) * 40 + q * 8;
    int lbW[4];
    #pragma unroll
    for (int kb = 0; kb < 4; ++kb) lbW[kb] = ((cg + 4 * kb) * 16 + nl) * 32 + q * 8;

    // x staging: thread -> (sample s_, channel cch within chunk of 32)
    const int s_ = tid >> 5, cch = tid & 31;
    const float* xg = x + ((size_t)(b0 + s_) * 256 + cch) * 16;
    _Float16* xd = &Xs[s_ * 656 + cch];

    floatx4 acc[2][4];
    #pragma unroll
    for (int rr = 0; rr < 2; ++rr)
        #pragma unroll
        for (int kb = 0; kb < 4; ++kb) acc[rr][kb] = floatx4{0.f, 0.f, 0.f, 0.f};

    floatx16 r = *(const floatx16*)xg;

    for (int cc = 0; cc < 8; ++cc) {
        __syncthreads();   // prior chunk's Xs readers done
        #pragma unroll
        for (int p = 0; p < 16; ++p) xd[p * 40] = (_Float16)r[p];
        {
            float sm = 0.f;
            #pragma unroll
            for (int p = 0; p < 16; ++p) sm += r[p];
            Pl[s_ * 264 + cc * 32 + cch] = (_Float16)(sm * (1.0f / 16.0f));
        }
        if (cc < 7) r = *(const floatx16*)(xg + (cc + 1) * 512);
        __syncthreads();   // Xs chunk ready

        #pragma unroll 3
        for (int ij = 0; ij < 9; ++ij) {
            const int step = cc * 9 + ij;
            const int p0 = (ij / 3) * 4 + (ij % 3);
            const _Float16* wstep = W3 + (size_t)step * 8192;
            half8 bF[4];
            #pragma unroll
            for (int kb = 0; kb < 4; ++kb) bF[kb] = *(const half8*)(wstep + lbW[kb]);
            half8 aF[2];
            #pragma unroll
            for (int rr = 0; rr < 2; ++rr)
                aF[rr] = *(const half8*)&Xs[(rh * 2 + rr) * 2624 + aLane + p0 * 40];
            #pragma unroll
            for (int rr = 0; rr < 2; ++rr)
                #pragma unroll
                for (int kb = 0; kb < 4; ++kb)
                    acc[rr][kb] = __builtin_amdgcn_mfma_f32_16x16x32_f16(aF[rr], bF[kb], acc[rr][kb], 0, 0, 0);
        }
    }

    // ---- fc1 via MFMA (waves 0-3): hid[16s][64h] = Pl @ fc1_w^T ----
    if (rh == 0) {
        floatx4 a1 = floatx4{0.f, 0.f, 0.f, 0.f};
        const _Float16* wfb = Wf3 + ((cg * 16 + nl) * 32 + q * 8);
        const _Float16* pb = &Pl[nl * 264 + q * 8];
        #pragma unroll
        for (int st = 0; st < 8; ++st) {
            const half8 aF = *(const half8*)(pb + st * 32);
            const half8 bF = *(const half8*)(wfb + st * 2048);
            a1 = __builtin_amdgcn_mfma_f32_16x16x32_f16(aF, bF, a1, 0, 0, 0);
        }
        const int h = cg * 16 + nl;
        const float fb = fc1_b[h];
        #pragma unroll
        for (int reg = 0; reg < 4; ++reg)
            hid_lds[(q * 4 + reg) * 68 + h] = fmaxf(a1[reg] + fb, 0.f);
    }
    __syncthreads();

    // ---- fc2 + softmax (wave 0) ----
    if (wv == 0) {
        const int s = lane >> 2, kb = lane & 3;
        float l = fc2_b[kb];
        #pragma unroll 8
        for (int h = 0; h < 64; ++h) l += hid_lds[s * 68 + h] * fc2_w[kb * 64 + h];
        float m = fmaxf(l, __shfl_xor(l, 1));
        m = fmaxf(m, __shfl_xor(m, 2));
        const float e = __expf((l - m) * (1.0f / 34.0f));
        float sm = e + __shfl_xor(e, 1);
        sm += __shfl_xor(sm, 2);
        attn_s[s][kb] = e / sm;
    }
    __syncthreads();   // attn ready; Xs/Pl dead -> Act region free

    // ---- epilogue: attn-combine in registers -> silu + bases -> Act ----
    {
        const int o = cg * 16 + nl;
        const float bb0 = bias[o], bb1 = bias[64 + o], bb2 = bias[128 + o], bb3 = bias[192 + o];
        #pragma unroll
        for (int rr = 0; rr < 2; ++rr) {
            const int s = (rh * 2 + rr) * 4 + q;
            const float a0 = attn_s[s][0], a1 = attn_s[s][1], a2 = attn_s[s][2], a3 = attn_s[s][3];
            const float badd = a0 * bb0 + a1 * bb1 + a2 * bb2 + a3 * bb3;
            float f[4];
            #pragma unroll
            for (int e = 0; e < 4; ++e)
                f[e] = a0 * acc[rr][0][e] + a1 * acc[rr][1][e]
                     + a2 * acc[rr][2][e] + a3 * acc[rr][3][e] + badd;
            half4v sv;
            #pragma unroll
            for (int e = 0; e < 4; ++e) {
                const float ex = __expf(-f[e]);
                sv[e] = (_Float16)(f[e] * __builtin_amdgcn_rcpf(1.f + ex));
            }
            *(half4v*)&Act[s * 2312 + o * 4] = sv;
            #pragma unroll
            for (int e = 0; e < 4; ++e)
                bases8(f[e], &Act[s * 2312 + 256 + (o * 4 + e) * 8]);
        }
    }
    __syncthreads();

    // ---- KAN GEMM: out[16s][64o] = Act[16][2304] @ Wk^T, split-K by rh ----
    {
        floatx4 a2 = floatx4{0.f, 0.f, 0.f, 0.f};
        const _Float16* wkb = Wk3 + ((size_t)(cg * 16 + nl) * 32 + q * 8);
        const _Float16* ab = &Act[nl * 2312 + q * 8];
        #pragma unroll 6
        for (int i = 0; i < 36; ++i) {
            const int st = rh * 36 + i;
            const half8 aF = *(const half8*)(ab + st * 32);
            const half8 bF = *(const half8*)(wkb + (size_t)st * 2048);
            a2 = __builtin_amdgcn_mfma_f32_16x16x32_f16(aF, bF, a2, 0, 0, 0);
        }
        if (rh == 1) *(floatx4*)&hid_lds[cg * 256 + lane * 4] = a2;
        __syncthreads();
        if (rh == 0) {
            const floatx4 p = *(const floatx4*)&hid_lds[cg * 256 + lane * 4];
            a2 = a2 + p;
            #pragma unroll
            for (int reg = 0; reg < 4; ++reg)
                out[(size_t)(b0 + q * 4 + reg) * 64 + cg * 16 + nl] = a2[reg];
        }
    }
}

extern "C" void kernel_launch(void* const* d_in, const int* in_sizes, int n_in,
                              void* d_out, int out_size, void* d_ws, size_t ws_size,
                              hipStream_t stream) {
    const float* x          = (const float*)d_in[0];
    const float* weight     = (const float*)d_in[1];
    const float* bias       = (const float*)d_in[2];
    const float* fc1_w      = (const float*)d_in[3];
    const float* fc1_b      = (const float*)d_in[4];
    const float* fc2_w      = (const float*)d_in[5];
    const float* fc2_b      = (const float*)d_in[6];
    const float* kan_base_w = (const float*)d_in[7];
    const float* kan_spline = (const float*)d_in[8];
    const float* kan_scaler = (const float*)d_in[9];
    float* out = (float*)d_out;

    // ws: W3 (72*8192 halves) | Wk3 (72*2048) | Wf3 (8*2048)
    _Float16* W3  = (_Float16*)d_ws;
    _Float16* Wk3 = W3 + (size_t)72 * 8192;
    _Float16* Wf3 = Wk3 + (size_t)72 * 2048;

    w3_transform<<<256, 256, 0, stream>>>(weight, W3);
    wk3_transform<<<80, 256, 0, stream>>>(kan_base_w, kan_spline, kan_scaler,
                                          fc1_w, Wk3, Wf3);
    fused_kernel<<<BT / MS, 512, 0, stream>>>(x, W3, Wk3, Wf3, bias, fc1_b,
                                              fc2_w, fc2_b, out);
}